// Round 9
// baseline (471.932 us; speedup 1.0000x reference)
//
#include <hip/hip_runtime.h>

// TopK-and-scatter: out[r,c] = x[r,c] if x[r,c] is among the top-64 of row r
// (ties at threshold broken by LOWEST column index, matching lax.top_k), else 0.
// R9 = R8 chassis (one row per 1024-thread block, 2 blocks/CU, loads->regs,
// positive-only 4096-bin histogram, shuffle suffix scan, packed-u64 fused rank)
// with the write phase removed from the critical path: the full row of ZEROS is
// stored at kernel start (no dependencies, overlaps the loads in one memory
// burst), and after select only the <=64 selected values are scatter-stored.
// Ordering: zero-stores complete at the first __syncthreads (vmcnt drain),
// scatter stores issue several barriers later to block-private rows -> safe.
// Exact bitwise-search slow path (block-uniform) for pathological rows.

typedef float f32x4 __attribute__((ext_vector_type(4)));
typedef unsigned int u32;
typedef unsigned long long u64;
typedef u32 u32x4 __attribute__((ext_vector_type(4)));

#define TPB   1024
#define COLS  32768
#define EPT   32
#define KSEL  64u
#define CAP   2048u

__device__ __forceinline__ u32 blockSum(u32 v, u32* wtot, int lane, int wid)
{
    #pragma unroll
    for (int off = 32; off >= 1; off >>= 1) v += __shfl_down(v, off);
    if (lane == 0) wtot[wid] = v;
    __syncthreads();
    u32 t = 0;
    #pragma unroll
    for (int w = 0; w < 16; ++w) t += wtot[w];
    __syncthreads();
    return t;
}

__global__ __launch_bounds__(TPB) void topk_scatter_kernel(
    const float* __restrict__ x, float* __restrict__ out)
{
    __shared__ u32 hist[4096];            // 16 KB
    __shared__ u64 candPk[CAP];           // 16 KB
    __shared__ u32 wtot[16];
    __shared__ int sBin;
    __shared__ u32 sAbove;
    __shared__ u32 candN;

    const int tid  = threadIdx.x;
    const int lane = tid & 63;
    const int wid  = tid >> 6;

    const long long row = blockIdx.x;
    const f32x4* __restrict__ xrow = (const f32x4*)(x + row * (long long)COLS);
    f32x4* __restrict__ orow       = (f32x4*)(out + row * (long long)COLS);
    float* __restrict__ orowS      = out + row * (long long)COLS;

    // ---- zero-fill the output row FIRST (independent stores, overlap loads) ----
    const f32x4 zval = (f32x4)(0.0f);
    #pragma unroll
    for (int j = 0; j < 8; ++j) orow[j * TPB + tid] = zval;

    // zero histogram + counters (ordered by barrier A)
    ((u32x4*)hist)[tid] = (u32x4)(0u);
    if (tid == 0) { sBin = -1; candN = 0u; }

    // ---- load row into registers (8 loads in flight, no LDS deps) ----
    u32 key[EPT];
    #pragma unroll
    for (int j = 0; j < 8; ++j) {
        const f32x4 v = xrow[j * TPB + tid];
        #pragma unroll
        for (int l = 0; l < 4; ++l) {
            const u32 b = __float_as_uint(v[l]);
            key[j * 4 + l] = b ^ ((u32)((int)b >> 31) | 0x80000000u);
        }
    }
    __syncthreads();                                   // A: zeros+stores drained

    // ---- positive-only histogram: bins = bits [30:19] ----
    #pragma unroll
    for (int e = 0; e < EPT; ++e) {
        const u32 k = key[e];
        if (k & 0x80000000u) atomicAdd(&hist[(k & 0x7fffffffu) >> 19], 1u);
    }
    __syncthreads();                                   // B: hist complete

    u32 need = KSEL;

    // ---- suffix scan: thread owns bins [4*tid, 4*tid+4) ----
    {
        const u32x4 h = ((const u32x4*)hist)[tid];
        const u32 ls3 = h[3];
        const u32 ls2 = h[2] + ls3;
        const u32 ls1 = h[1] + ls2;
        const u32 ls0 = h[0] + ls1;
        u32 v = ls0;                                   // wave suffix scan (shfl)
        #pragma unroll
        for (int off = 1; off < 64; off <<= 1) {
            const u32 t = __shfl_down(v, off);
            if (lane + off < 64) v += t;
        }
        if (lane == 0) wtot[wid] = v;
        __syncthreads();                               // C: wtot ready
        u32 tailWaves = 0u;
        for (int w = wid + 1; w < 16; ++w) tailWaves += wtot[w];
        const u32 thrTail = tailWaves + (v - ls0);
        const u32 S0 = ls0 + thrTail, S1 = ls1 + thrTail, S2 = ls2 + thrTail,
                  S3 = ls3 + thrTail, S4 = thrTail;
        if (S0 >= need && S1 < need) { sBin = 4 * tid + 0; sAbove = S1; }
        if (S1 >= need && S2 < need) { sBin = 4 * tid + 1; sAbove = S2; }
        if (S2 >= need && S3 < need) { sBin = 4 * tid + 2; sAbove = S3; }
        if (S3 >= need && S4 < need) { sBin = 4 * tid + 3; sAbove = S4; }
        __syncthreads();                               // D: crossing known
    }
    const int b1s = sBin;                              // snapshot
    const u32 above = sAbove;
    bool fast = (b1s >= 0);
    u32 b1 = 0, C = 0;

    if (fast) {
        b1 = (u32)b1s;
        need = KSEL - above;                           // 1 <= need <= count(b1)
        // ---- collect crossing-bin candidates, packed (key desc, col asc) ----
        #pragma unroll
        for (int e = 0; e < EPT; ++e) {
            const u32 k = key[e];
            if ((k & 0x80000000u) && ((k & 0x7fffffffu) >> 19) == b1) {
                const u32 p = atomicAdd(&candN, 1u);
                if (p < CAP) {
                    const u32 col = (u32)(((e >> 2) * TPB + tid) * 4 + (e & 3));
                    candPk[p] = ((u64)k << 32) | (u32)(~col);
                }
            }
        }
        __syncthreads();                               // E: candidates ready
        C = candN;                                     // snapshot
        fast = (C <= CAP);
    }

    if (fast) {
        // ---- sparse scatter: only selected elements are stored ----
        #pragma unroll
        for (int e = 0; e < EPT; ++e) {
            const u32 k = key[e];
            if (k & 0x80000000u) {
                const u32 kb = (k & 0x7fffffffu) >> 19;
                if (kb >= b1) {
                    const u32 col = (u32)(((e >> 2) * TPB + tid) * 4 + (e & 3));
                    bool sel = (kb > b1);
                    if (!sel) {
                        const u64 me = ((u64)k << 32) | (u32)(~col);
                        u32 r = 0;
                        for (u32 q = 0; q < C; ++q)    // LDS b64 broadcast
                            r += (candPk[q] > me) ? 1u : 0u;
                        sel = (r < need);
                    }
                    if (sel) orowS[col] = __uint_as_float(k ^ 0x80000000u);
                }
            }
        }
    } else {
        // ---- exact slow path (any input): bitwise searches ----
        u32 pfx = 0u;
        for (int bit = 31; bit >= 0; --bit) {
            const u32 trial = pfx | (1u << bit);
            u32 loc = 0u;
            #pragma unroll
            for (int e = 0; e < EPT; ++e) loc += (key[e] >= trial) ? 1u : 0u;
            if (blockSum(loc, wtot, lane, wid) >= KSEL) pfx = trial;
        }
        const u32 T = pfx;                             // 64th largest key
        u32 loc = 0u;
        #pragma unroll
        for (int e = 0; e < EPT; ++e) loc += (key[e] > T) ? 1u : 0u;
        const u32 needEq = KSEL - blockSum(loc, wtot, lane, wid);
        u32 cv = 0u;
        for (int bit = 14; bit >= 0; --bit) {
            const u32 trial = cv | (1u << bit);
            u32 l2 = 0u;
            #pragma unroll
            for (int e = 0; e < EPT; ++e) {
                const u32 col = (u32)(((e >> 2) * TPB + tid) * 4 + (e & 3));
                l2 += (key[e] == T && col < trial) ? 1u : 0u;
            }
            if (blockSum(l2, wtot, lane, wid) < needEq) cv = trial;
        }
        const u32 colT = cv;                           // needEq-th smallest eq col
        #pragma unroll
        for (int e = 0; e < EPT; ++e) {
            const u32 k = key[e];
            const u32 col = (u32)(((e >> 2) * TPB + tid) * 4 + (e & 3));
            if ((k > T) || (k == T && col <= colT)) {
                orowS[col] = __uint_as_float(
                    (k & 0x80000000u) ? (k ^ 0x80000000u) : ~k);
            }
        }
    }
}

extern "C" void kernel_launch(void* const* d_in, const int* in_sizes, int n_in,
                              void* d_out, int out_size, void* d_ws, size_t ws_size,
                              hipStream_t stream)
{
    (void)n_in; (void)out_size; (void)d_ws; (void)ws_size;
    const float* x = (const float*)d_in[0];
    float* out = (float*)d_out;
    const int rows = in_sizes[0] / COLS;
    topk_scatter_kernel<<<dim3(rows), dim3(TPB), 0, stream>>>(x, out);
}